// Round 1
// baseline (1122.961 us; speedup 1.0000x reference)
//
#include <hip/hip_runtime.h>
#include <math.h>

#define B_N 4096
#define D_DIM 512
#define MARGIN 0.2f
#define PAIR_EPS 1e-8f
#define NEG_INF (-INFINITY)

// ws layout (bytes):
//   0    : float accum[2]  (total, count)
//   4096 : float sq[B_N]
constexpr size_t WS_SQ_OFF = 4096;

constexpr int IT = 16;           // i-rows per block
constexpr int NW = 8;            // waves per block (512 threads)
constexpr int JT = NW * 64;      // 512 j per pass
constexpr int NPASS = B_N / JT;  // 8
constexpr int KC = 32;           // k-chunk (floats)

__global__ __launch_bounds__(256) void k_prep(const float* __restrict__ batch,
                                              float* __restrict__ accum,
                                              float* __restrict__ sq) {
  if (blockIdx.x == 0 && threadIdx.x == 0) { accum[0] = 0.f; accum[1] = 0.f; }
  int row  = blockIdx.x * 4 + (threadIdx.x >> 6);
  int lane = threadIdx.x & 63;
  const float* x = batch + (size_t)row * D_DIM;
  float s = 0.f;
#pragma unroll
  for (int e = 0; e < 2; ++e) {
    float4 v = *(const float4*)(x + lane * 4 + e * 256);
    s += v.x * v.x + v.y * v.y + v.z * v.z + v.w * v.w;
  }
#pragma unroll
  for (int off = 32; off; off >>= 1) s += __shfl_xor(s, off);
  if (lane == 0) sq[row] = s;
}

__global__ __launch_bounds__(512, 2) void k_main(
    const float* __restrict__ batch, const float* __restrict__ beta,
    const float* __restrict__ gpos, const float* __restrict__ gneg,
    const int* __restrict__ labels, const float* __restrict__ sq,
    float* __restrict__ accum) {
  __shared__ float2 red_neg[NW][IT];
  __shared__ float2 red_pos[NW][IT];
  __shared__ int s_negidx[IT];
  __shared__ int s_posidx[IT];

  const int wave = threadIdx.x >> 6;
  const int lane = threadIdx.x & 63;
  const int i0   = blockIdx.x * IT;

  float nbv[IT]; int nbi[IT];
  float pbv[IT]; int pbi[IT];
#pragma unroll
  for (int i = 0; i < IT; ++i) {
    nbv[i] = NEG_INF; nbi[i] = 0;
    pbv[i] = NEG_INF; pbi[i] = 0;
  }

  for (int t = 0; t < NPASS; ++t) {
    const int j = t * JT + wave * 64 + lane;   // this lane's column
    const float* xj = batch + (size_t)j * D_DIM;

    float acc[IT];
#pragma unroll
    for (int i = 0; i < IT; ++i) acc[i] = 0.f;

    for (int k0 = 0; k0 < D_DIM; k0 += KC) {
      float4 xjv[KC / 4];
#pragma unroll
      for (int e = 0; e < KC / 4; ++e) xjv[e] = *(const float4*)(xj + k0 + e * 4);
#pragma unroll
      for (int i = 0; i < IT; ++i) {
        const float* xi = batch + (size_t)(i0 + i) * D_DIM + k0;  // wave-uniform -> s_load
        float s = acc[i];
#pragma unroll
        for (int e = 0; e < KC / 4; ++e) {
          float4 xv = *(const float4*)(xi + e * 4);
          s += xv.x * xjv[e].x;
          s += xv.y * xjv[e].y;
          s += xv.z * xjv[e].z;
          s += xv.w * xjv[e].w;
        }
        acc[i] = s;
      }
    }

    const int   lj  = labels[j];
    const float sqj = sq[j];
#pragma unroll
    for (int i = 0; i < IT; ++i) {
      const int   gi  = i0 + i;
      const int   li  = labels[gi];   // uniform
      const float sqi = sq[gi];       // uniform
      const bool  same = (li == lj);
      float d2 = sqi + sqj - 2.f * acc[i];
      // dist = max(sqrt(max(d2,1e-4)),0.5)  =>  dist^2 = max(d2, 0.25)
      float e2 = fmaxf(fmaxf(d2, 0.f), 0.25f);
      // log_q = -255*log(e2) - 254.5*log(1 - 0.25*e2)
      float logq = -255.f * logf(e2) - 254.5f * logf(1.f - 0.25f * e2);
      float nv = NEG_INF;
      if (!same) nv = logq + gneg[(size_t)gi * B_N + j];
      if (nv > nbv[i]) { nbv[i] = nv; nbi[i] = j; }
      float pv = NEG_INF;
      if (same && j != gi) pv = gpos[(size_t)gi * B_N + j];
      if (pv > pbv[i]) { pbv[i] = pv; pbi[i] = j; }
    }
  }

  // per-i cross-lane argmax (first-index tie-break), then stash per-wave winner
#pragma unroll
  for (int i = 0; i < IT; ++i) {
    float v = nbv[i]; int ix = nbi[i];
#pragma unroll
    for (int off = 32; off; off >>= 1) {
      float ov = __shfl_xor(v, off);
      int   oi = __shfl_xor(ix, off);
      if (ov > v || (ov == v && oi < ix)) { v = ov; ix = oi; }
    }
    if (lane == 0) red_neg[wave][i] = make_float2(v, __int_as_float(ix));
    v = pbv[i]; ix = pbi[i];
#pragma unroll
    for (int off = 32; off; off >>= 1) {
      float ov = __shfl_xor(v, off);
      int   oi = __shfl_xor(ix, off);
      if (ov > v || (ov == v && oi < ix)) { v = ov; ix = oi; }
    }
    if (lane == 0) red_pos[wave][i] = make_float2(v, __int_as_float(ix));
  }
  __syncthreads();

  if (wave == 0 && lane < IT) {
    float bv = NEG_INF; int bi = 0;
    for (int w = 0; w < NW; ++w) {
      float2 e = red_neg[w][lane];
      int ei = __float_as_int(e.y);
      if (e.x > bv || (e.x == bv && ei < bi)) { bv = e.x; bi = ei; }
    }
    s_negidx[lane] = (bv == NEG_INF) ? 0 : bi;
  }
  if (wave == 1 && lane < IT) {
    float bv = NEG_INF; int bi = 0;
    for (int w = 0; w < NW; ++w) {
      float2 e = red_pos[w][lane];
      int ei = __float_as_int(e.y);
      if (e.x > bv || (e.x == bv && ei < bi)) { bv = e.x; bi = ei; }
    }
    s_posidx[lane] = (bv == NEG_INF) ? 0 : bi;
  }
  __syncthreads();

  // triplet-loss tail: each wave handles IT/NW rows
#pragma unroll
  for (int rr = 0; rr < IT / NW; ++rr) {
    const int i  = wave * (IT / NW) + rr;
    const int gi = i0 + i;
    const float* xi = batch + (size_t)gi * D_DIM;
    const float* xp = batch + (size_t)s_posidx[i] * D_DIM;
    const float* xn = batch + (size_t)s_negidx[i] * D_DIM;
    float sap = 0.f, san = 0.f;
#pragma unroll
    for (int e = 0; e < 2; ++e) {
      float4 a = *(const float4*)(xi + lane * 4 + e * 256);
      float4 p = *(const float4*)(xp + lane * 4 + e * 256);
      float4 n = *(const float4*)(xn + lane * 4 + e * 256);
      float dx = a.x - p.x, dy = a.y - p.y, dz = a.z - p.z, dw = a.w - p.w;
      sap += dx * dx + dy * dy + dz * dz + dw * dw;
      dx = a.x - n.x; dy = a.y - n.y; dz = a.z - n.z; dw = a.w - n.w;
      san += dx * dx + dy * dy + dz * dz + dw * dw;
    }
#pragma unroll
    for (int off = 32; off; off >>= 1) {
      sap += __shfl_xor(sap, off);
      san += __shfl_xor(san, off);
    }
    if (lane == 0) {
      float d_ap = sqrtf(sap + PAIR_EPS);
      float d_an = sqrtf(san + PAIR_EPS);
      float b = beta[labels[gi]];
      float pl = fmaxf(d_ap - b + MARGIN, 0.f);
      float nl = fmaxf(b - d_an + MARGIN, 0.f);
      float cnt = (pl > 0.f ? 1.f : 0.f) + (nl > 0.f ? 1.f : 0.f);
      atomicAdd(&accum[0], pl + nl);
      atomicAdd(&accum[1], cnt);
    }
  }
}

__global__ void k_final(const float* __restrict__ accum, float* __restrict__ out) {
  float tot = accum[0], cnt = accum[1];
  out[0] = (cnt == 0.f) ? tot : tot / cnt;
}

extern "C" void kernel_launch(void* const* d_in, const int* in_sizes, int n_in,
                              void* d_out, int out_size, void* d_ws, size_t ws_size,
                              hipStream_t stream) {
  const float* batch  = (const float*)d_in[0];
  const float* beta   = (const float*)d_in[1];
  const float* gpos   = (const float*)d_in[2];
  const float* gneg   = (const float*)d_in[3];
  const int*   labels = (const int*)d_in[4];
  float* out   = (float*)d_out;
  float* accum = (float*)d_ws;
  float* sq    = (float*)((char*)d_ws + WS_SQ_OFF);

  k_prep<<<B_N / 4, 256, 0, stream>>>(batch, accum, sq);
  k_main<<<B_N / IT, 512, 0, stream>>>(batch, beta, gpos, gneg, labels, sq, accum);
  k_final<<<1, 1, 0, stream>>>(accum, out);
}

// Round 2
// 412.849 us; speedup vs baseline: 2.7200x; 2.7200x over previous
//
#include <hip/hip_runtime.h>
#include <math.h>

#define B_N 4096
#define D_DIM 512
#define MARGIN 0.2f
#define PAIR_EPS 1e-8f
#define NEG_INF (-INFINITY)

typedef __attribute__((ext_vector_type(8))) short bf16x8;
typedef __attribute__((ext_vector_type(4))) float f32x4;

// ws layout (bytes) — needs ~10.1 MB total:
//   0x000000 : float accum[2] (total, count)
//   0x001000 : float sq[4096]            (16 KB)
//   0x010000 : ushort Xh[4096*512]       (4 MB)
//   0x410000 : ushort Xl[4096*512]       (4 MB)
//   0x810000 : float4 part[32*32][128]   (2 MB)  per (ib,jb): 128 rows of (nv,nix,pv,pix)
constexpr size_t WS_SQ   = 0x1000;
constexpr size_t WS_XH   = 0x10000;
constexpr size_t WS_XL   = 0x410000;
constexpr size_t WS_PART = 0x810000;

__device__ __forceinline__ unsigned short f2bf(float f) {
  unsigned int u = __float_as_uint(f);
  unsigned int r = (u + 0x7fffu + ((u >> 16) & 1u)) >> 16;  // RNE
  return (unsigned short)r;
}
__device__ __forceinline__ float bf2f(unsigned short h) {
  return __uint_as_float(((unsigned int)h) << 16);
}

typedef __attribute__((address_space(1))) const void* gptr_t;
typedef __attribute__((address_space(3))) void* lptr_t;
__device__ __forceinline__ void gload_lds16(const void* g, void* l) {
  __builtin_amdgcn_global_load_lds((gptr_t)g, (lptr_t)l, 16, 0, 0);
}

// ---------------- prep: fp32 -> bf16 hi/lo split ----------------
__global__ __launch_bounds__(256) void k_convert(const float* __restrict__ batch,
                                                 unsigned short* __restrict__ xh,
                                                 unsigned short* __restrict__ xl) {
  size_t t = (size_t)blockIdx.x * 256 + threadIdx.x;  // 524288 threads, 4 floats each
  float4 v = ((const float4*)batch)[t];
  ushort4 h, l;
  h.x = f2bf(v.x); l.x = f2bf(v.x - bf2f(h.x));
  h.y = f2bf(v.y); l.y = f2bf(v.y - bf2f(h.y));
  h.z = f2bf(v.z); l.z = f2bf(v.z - bf2f(h.z));
  h.w = f2bf(v.w); l.w = f2bf(v.w - bf2f(h.w));
  ((ushort4*)xh)[t] = h;
  ((ushort4*)xl)[t] = l;
}

// ---------------- prep: row squared-norms + accum init ----------------
__global__ __launch_bounds__(256) void k_sq(const float* __restrict__ batch,
                                            float* __restrict__ accum,
                                            float* __restrict__ sq) {
  if (blockIdx.x == 0 && threadIdx.x == 0) { accum[0] = 0.f; accum[1] = 0.f; }
  int row  = blockIdx.x * 4 + (threadIdx.x >> 6);
  int lane = threadIdx.x & 63;
  const float* x = batch + (size_t)row * D_DIM;
  float s = 0.f;
#pragma unroll
  for (int e = 0; e < 2; ++e) {
    float4 v = *(const float4*)(x + lane * 4 + e * 256);
    s += v.x * v.x + v.y * v.y + v.z * v.z + v.w * v.w;
  }
#pragma unroll
  for (int off = 32; off; off >>= 1) s += __shfl_xor(s, off);
  if (lane == 0) sq[row] = s;
}

// ---------------- GEMM (3-pass hi/lo, K'=1536) + fused epilogue ----------------
__global__ __launch_bounds__(256) void k_gemm(
    const unsigned short* __restrict__ Xh, const unsigned short* __restrict__ Xl,
    const float* __restrict__ gpos, const float* __restrict__ gneg,
    const int* __restrict__ labels, const float* __restrict__ sq,
    float4* __restrict__ part) {
  __shared__ unsigned short As[128 * 64];
  __shared__ unsigned short Bs[128 * 64];
  __shared__ float4 red[128][2];
  __shared__ float s_sqj[128];
  __shared__ int   s_lbj[128];
  __shared__ float s_sqi[128];
  __shared__ int   s_lbi[128];

  const int jb = blockIdx.x, ib = blockIdx.y;
  const int i0 = ib * 128, j0 = jb * 128;
  const int tid = threadIdx.x;
  const int w = tid >> 6, lane = tid & 63;
  const int wr = (w >> 1) * 64, wc = (w & 1) * 64;   // wave's 64x64 quadrant
  const int lr = lane & 15, lk = (lane >> 4) * 8;

  if (tid < 128) { s_sqj[tid] = sq[j0 + tid]; s_lbj[tid] = labels[j0 + tid]; }
  else { int t = tid - 128; s_sqi[t] = sq[i0 + t]; s_lbi[t] = labels[i0 + t]; }

  f32x4 acc[4][4] = {};

  // staging lane geometry: 8 rows x 128B per wave-issue
  const int srow = lane >> 3;          // 0..7
  const int scol = (lane & 7) * 8;     // bf16 elems, 16B per lane

  for (int ks = 0; ks < 24; ++ks) {
    const int phase = ks >> 3;  // 0: Ah*Bh, 1: Ah*Bl, 2: Al*Bh
    const unsigned short* Asrc = (phase < 2) ? Xh : Xl;
    const unsigned short* Bsrc = (phase == 1) ? Xl : Xh;
    const int kk = (ks & 7) * 64;
#pragma unroll
    for (int q = 0; q < 4; ++q) {
      int r0 = q * 32 + w * 8;
      int row = r0 + srow;
      gload_lds16(Asrc + ((size_t)(i0 + row) * D_DIM + kk + scol), &As[r0 * 64]);
      gload_lds16(Bsrc + ((size_t)(j0 + row) * D_DIM + kk + scol), &Bs[r0 * 64]);
    }
    __syncthreads();
#pragma unroll
    for (int kk2 = 0; kk2 < 64; kk2 += 32) {
      bf16x8 af[4], bfr[4];
#pragma unroll
      for (int mi = 0; mi < 4; ++mi)
        af[mi] = *(const bf16x8*)&As[(wr + mi * 16 + lr) * 64 + kk2 + lk];
#pragma unroll
      for (int ni = 0; ni < 4; ++ni)
        bfr[ni] = *(const bf16x8*)&Bs[(wc + ni * 16 + lr) * 64 + kk2 + lk];
#pragma unroll
      for (int mi = 0; mi < 4; ++mi)
#pragma unroll
        for (int ni = 0; ni < 4; ++ni)
          acc[mi][ni] = __builtin_amdgcn_mfma_f32_16x16x32_bf16(af[mi], bfr[ni], acc[mi][ni], 0, 0, 0);
    }
    __syncthreads();
  }

  // ---- fused epilogue: d2 -> log_q -> +gumbel -> per-row argmax over this j-tile ----
#pragma unroll
  for (int mi = 0; mi < 4; ++mi) {
#pragma unroll
    for (int r = 0; r < 4; ++r) {
      const int lrow = wr + mi * 16 + (lane >> 4) * 4 + r;
      const int gi = i0 + lrow;
      const int li = s_lbi[lrow];
      const float sqi = s_sqi[lrow];
      float nv = NEG_INF; int nix = 0;
      float pv = NEG_INF; int pix = 0;
#pragma unroll
      for (int ni = 0; ni < 4; ++ni) {
        const int cj = wc + ni * 16 + lr;
        const int gj = j0 + cj;
        const float g = acc[mi][ni][r];
        float d2 = sqi + s_sqj[cj] - 2.f * g;
        float e2 = fmaxf(d2, 0.25f);   // dist clamps (1e-4 then 0.5) => dist^2 = max(d2,0.25)
        float lq = -255.f * __logf(e2) - 254.5f * __logf(1.f - 0.25f * e2);
        const bool same = (li == s_lbj[cj]);
        float cn = same ? NEG_INF : lq + gneg[(size_t)gi * B_N + gj];
        if (cn > nv) { nv = cn; nix = gj; }
        float cp = NEG_INF;
        if (same & (gi != gj)) cp = gpos[(size_t)gi * B_N + gj];
        if (cp > pv) { pv = cp; pix = gj; }
      }
      // reduce across the 16 lanes sharing this row (low 4 lane bits)
#pragma unroll
      for (int off = 1; off < 16; off <<= 1) {
        float onv = __shfl_xor(nv, off); int onix = __shfl_xor(nix, off);
        if (onv > nv || (onv == nv && onix < nix)) { nv = onv; nix = onix; }
        float opv = __shfl_xor(pv, off); int opix = __shfl_xor(pix, off);
        if (opv > pv || (opv == pv && opix < pix)) { pv = opv; pix = opix; }
      }
      if (lr == 0) red[lrow][w & 1] = make_float4(nv, __int_as_float(nix), pv, __int_as_float(pix));
    }
  }
  __syncthreads();
  if (tid < 128) {
    float4 a = red[tid][0], b = red[tid][1];   // a covers lower cols: ties -> a
    float nv = a.x; int nix = __float_as_int(a.y);
    if (b.x > nv) { nv = b.x; nix = __float_as_int(b.y); }
    float pv = a.z; int pix = __float_as_int(a.w);
    if (b.z > pv) { pv = b.z; pix = __float_as_int(b.w); }
    part[((size_t)ib * 32 + jb) * 128 + tid] =
        make_float4(nv, __int_as_float(nix), pv, __int_as_float(pix));
  }
}

// ---------------- final argmax across j-tiles + triplet loss ----------------
__global__ __launch_bounds__(512) void k_reduce(const float* __restrict__ batch,
                                                const float* __restrict__ beta,
                                                const int* __restrict__ labels,
                                                const float4* __restrict__ part,
                                                float* __restrict__ accum) {
  const int wave = threadIdx.x >> 6, lane = threadIdx.x & 63;
  const int row = blockIdx.x * 8 + wave;
  float nv = NEG_INF, pv = NEG_INF;
  int nix = 0x7fffffff, pix = 0x7fffffff;
  if (lane < 32) {
    float4 p = part[((size_t)(row >> 7) * 32 + lane) * 128 + (row & 127)];
    nv = p.x; nix = __float_as_int(p.y);
    pv = p.z; pix = __float_as_int(p.w);
  }
#pragma unroll
  for (int off = 16; off; off >>= 1) {   // lanes 0..31 reduce among themselves
    float onv = __shfl_xor(nv, off); int onix = __shfl_xor(nix, off);
    if (onv > nv || (onv == nv && onix < nix)) { nv = onv; nix = onix; }
    float opv = __shfl_xor(pv, off); int opix = __shfl_xor(pix, off);
    if (opv > pv || (opv == pv && opix < pix)) { pv = opv; pix = opix; }
  }
  nix = __shfl(nix, 0); pix = __shfl(pix, 0);

  const float* xi = batch + (size_t)row * D_DIM;
  const float* xp = batch + (size_t)pix * D_DIM;
  const float* xn = batch + (size_t)nix * D_DIM;
  float sap = 0.f, san = 0.f;
#pragma unroll
  for (int e = 0; e < 2; ++e) {
    float4 a = ((const float4*)xi)[lane * 2 + e];
    float4 p = ((const float4*)xp)[lane * 2 + e];
    float4 n = ((const float4*)xn)[lane * 2 + e];
    float dx = a.x - p.x, dy = a.y - p.y, dz = a.z - p.z, dw = a.w - p.w;
    sap += dx * dx + dy * dy + dz * dz + dw * dw;
    dx = a.x - n.x; dy = a.y - n.y; dz = a.z - n.z; dw = a.w - n.w;
    san += dx * dx + dy * dy + dz * dz + dw * dw;
  }
#pragma unroll
  for (int off = 32; off; off >>= 1) {
    sap += __shfl_xor(sap, off);
    san += __shfl_xor(san, off);
  }
  if (lane == 0) {
    float d_ap = sqrtf(sap + PAIR_EPS);
    float d_an = sqrtf(san + PAIR_EPS);
    float b = beta[labels[row]];
    float pl = fmaxf(d_ap - b + MARGIN, 0.f);
    float nl = fmaxf(b - d_an + MARGIN, 0.f);
    float cnt = (pl > 0.f ? 1.f : 0.f) + (nl > 0.f ? 1.f : 0.f);
    atomicAdd(&accum[0], pl + nl);
    atomicAdd(&accum[1], cnt);
  }
}

__global__ void k_final(const float* __restrict__ accum, float* __restrict__ out) {
  float tot = accum[0], cnt = accum[1];
  out[0] = (cnt == 0.f) ? tot : tot / cnt;
}

extern "C" void kernel_launch(void* const* d_in, const int* in_sizes, int n_in,
                              void* d_out, int out_size, void* d_ws, size_t ws_size,
                              hipStream_t stream) {
  const float* batch  = (const float*)d_in[0];
  const float* beta   = (const float*)d_in[1];
  const float* gpos   = (const float*)d_in[2];
  const float* gneg   = (const float*)d_in[3];
  const int*   labels = (const int*)d_in[4];
  float* out = (float*)d_out;

  float*          accum = (float*)d_ws;
  float*          sq    = (float*)((char*)d_ws + WS_SQ);
  unsigned short* xh    = (unsigned short*)((char*)d_ws + WS_XH);
  unsigned short* xl    = (unsigned short*)((char*)d_ws + WS_XL);
  float4*         part  = (float4*)((char*)d_ws + WS_PART);

  k_convert<<<2048, 256, 0, stream>>>(batch, xh, xl);
  k_sq<<<B_N / 4, 256, 0, stream>>>(batch, accum, sq);
  dim3 g(32, 32);
  k_gemm<<<g, 256, 0, stream>>>(xh, xl, gpos, gneg, labels, sq, part);
  k_reduce<<<B_N / 8, 512, 0, stream>>>(batch, beta, labels, part, accum);
  k_final<<<1, 1, 0, stream>>>(accum, out);
}

// Round 5
// 290.106 us; speedup vs baseline: 3.8709x; 1.4231x over previous
//
#include <hip/hip_runtime.h>
#include <math.h>

#define B_N 4096
#define D_DIM 512
#define MARGIN 0.2f
#define PAIR_EPS 1e-8f
#define NEG_INF (-INFINITY)

typedef __attribute__((ext_vector_type(8))) short bf16x8;
typedef __attribute__((ext_vector_type(4))) float f32x4;

// ws layout (bytes):
//   0x000000 : float accum[2] (total, count)
//   0x001000 : float sq[4096]
//   0x010000 : ushort Xh[4096*512]   (4 MB)
//   0x410000 : ushort Xl[4096*512]   (4 MB)
//   0x810000 : float4 part[16*16][256] (1 MB)
constexpr size_t WS_SQ   = 0x1000;
constexpr size_t WS_XH   = 0x10000;
constexpr size_t WS_XL   = 0x410000;
constexpr size_t WS_PART = 0x810000;

__device__ __forceinline__ unsigned short f2bf(float f) {
  unsigned int u = __float_as_uint(f);
  unsigned int r = (u + 0x7fffu + ((u >> 16) & 1u)) >> 16;  // RNE
  return (unsigned short)r;
}
__device__ __forceinline__ float bf2f(unsigned short h) {
  return __uint_as_float(((unsigned int)h) << 16);
}

typedef __attribute__((address_space(1))) const void* gptr_t;
typedef __attribute__((address_space(3))) void* lptr_t;
__device__ __forceinline__ void gload_lds16(const void* g, void* l) {
  __builtin_amdgcn_global_load_lds((gptr_t)g, (lptr_t)l, 16, 0, 0);
}

// ---------------- prep: accum init + sq + bf16 hi/lo split (fused) ----------------
__global__ __launch_bounds__(256) void k_prep(const float* __restrict__ batch,
                                              float* __restrict__ accum,
                                              float* __restrict__ sq,
                                              unsigned short* __restrict__ xh,
                                              unsigned short* __restrict__ xl) {
  if (blockIdx.x == 0 && threadIdx.x == 0) { accum[0] = 0.f; accum[1] = 0.f; }
  int row  = blockIdx.x * 4 + (threadIdx.x >> 6);
  int lane = threadIdx.x & 63;
  const size_t base = (size_t)row * D_DIM;
  float s = 0.f;
#pragma unroll
  for (int e = 0; e < 2; ++e) {
    const int off = lane * 4 + e * 256;
    float4 v = *(const float4*)(batch + base + off);
    ushort4 h, l;
    h.x = f2bf(v.x); l.x = f2bf(v.x - bf2f(h.x));
    h.y = f2bf(v.y); l.y = f2bf(v.y - bf2f(h.y));
    h.z = f2bf(v.z); l.z = f2bf(v.z - bf2f(h.z));
    h.w = f2bf(v.w); l.w = f2bf(v.w - bf2f(h.w));
    *(ushort4*)(xh + base + off) = h;
    *(ushort4*)(xl + base + off) = l;
    s += v.x * v.x + v.y * v.y + v.z * v.z + v.w * v.w;
  }
#pragma unroll
  for (int off = 32; off; off >>= 1) s += __shfl_xor(s, off);
  if (lane == 0) sq[row] = s;
}

// ---------------- GEMM: 256x256 tile, dbuf 2-phase, T2 swizzle, fused epilogue ----
// Virtual K = 1536: k-tile t in [0,24), phase p = t>>3 selects (Ah,Bh)/(Ah,Bl)/(Al,Bh).
__global__ __launch_bounds__(512, 2) void k_gemm(
    const unsigned short* __restrict__ Xh, const unsigned short* __restrict__ Xl,
    const float* __restrict__ gpos, const float* __restrict__ gneg,
    const int* __restrict__ labels, const float* __restrict__ sq,
    float4* __restrict__ part) {
  __shared__ unsigned short As[2][256 * 64];   // 32KB x2
  __shared__ unsigned short Bs[2][256 * 64];   // 32KB x2
  __shared__ float s_sqi[256], s_sqj[256];
  __shared__ int   s_lbi[256], s_lbj[256];

  const int jb = blockIdx.x, ib = blockIdx.y;
  const int i0 = ib * 256, j0 = jb * 256;
  const int tid = threadIdx.x;
  const int w = tid >> 6, lane = tid & 63;
  const int wm = w & 1, wn = w >> 1;          // 2 (M) x 4 (N) wave grid
  const int lr = lane & 15;                    // fragment row-lane
  const int lk = (lane >> 4) * 8;              // fragment k-offset (elems)

  if (tid < 256)      { s_sqi[tid] = sq[i0 + tid];       s_lbi[tid] = labels[i0 + tid]; }
  else                { int t = tid - 256; s_sqj[t] = sq[j0 + t]; s_lbj[t] = labels[j0 + t]; }

  f32x4 acc[8][4] = {};

  // staging geometry: issue q covers tile rows [q*64 + w*8, +8), 8 lanes x 16B per row.
  // LDS dest is linear (gload_lds: base + lane*16). Source column is inverse-swizzled
  // so that ds_read with byte^((row&7)<<4) returns linear data (rule #21).
  const int srow = lane >> 3;                                  // 0..7
  const int scol = (((lane & 7) ^ (lane >> 3)) << 3);          // elems, swizzled

#define STAGE(c, t)                                                              \
  {                                                                              \
    const int p_ = (t) >> 3;                                                     \
    const unsigned short* Asrc = (p_ < 2) ? Xh : Xl;                             \
    const unsigned short* Bsrc = (p_ == 1) ? Xl : Xh;                            \
    const int kk_ = ((t) & 7) * 64;                                              \
    _Pragma("unroll")                                                            \
    for (int q = 0; q < 4; ++q) {                                                \
      const int row = q * 64 + w * 8 + srow;                                     \
      gload_lds16(Asrc + ((size_t)(i0 + row) << 9) + kk_ + scol,                 \
                  &As[c][q * 4096 + w * 512]);                                   \
      gload_lds16(Bsrc + ((size_t)(j0 + row) << 9) + kk_ + scol,                 \
                  &Bs[c][q * 4096 + w * 512]);                                   \
    }                                                                            \
  }

  STAGE(0, 0);
  __syncthreads();

  int cur = 0;
  for (int t = 0; t < 24; ++t) {
    if (t + 1 < 24) STAGE(cur ^ 1, t + 1);
    const char* Ab = (const char*)&As[cur][0];
    const char* Bb = (const char*)&Bs[cur][0];
#pragma unroll
    for (int kk2 = 0; kk2 < 64; kk2 += 32) {
      bf16x8 af[8], bfv[4];
#pragma unroll
      for (int mi = 0; mi < 8; ++mi) {
        const int row = wm * 128 + mi * 16 + lr;
        const int byt = ((row << 7) + ((kk2 + lk) << 1)) ^ ((lane & 7) << 4);
        af[mi] = *(const bf16x8*)(Ab + byt);
      }
#pragma unroll
      for (int ni = 0; ni < 4; ++ni) {
        const int row = wn * 64 + ni * 16 + lr;
        const int byt = ((row << 7) + ((kk2 + lk) << 1)) ^ ((lane & 7) << 4);
        bfv[ni] = *(const bf16x8*)(Bb + byt);
      }
      __builtin_amdgcn_s_setprio(1);
#pragma unroll
      for (int mi = 0; mi < 8; ++mi)
#pragma unroll
        for (int ni = 0; ni < 4; ++ni)
          acc[mi][ni] = __builtin_amdgcn_mfma_f32_16x16x32_bf16(af[mi], bfv[ni], acc[mi][ni], 0, 0, 0);
      __builtin_amdgcn_s_setprio(0);
    }
    __syncthreads();   // drains vmcnt+lgkmcnt: staged buf ready, reads of cur done
    cur ^= 1;
  }

  // ---- fused epilogue: d2 -> log_q -> +gumbel -> per-row argmax over this j-tile ----
  float4* red = (float4*)&As[0][0];   // alias (main loop done); 256 rows x 4 wn = 16KB
#pragma unroll
  for (int mi = 0; mi < 8; ++mi) {
#pragma unroll
    for (int r = 0; r < 4; ++r) {
      const int lrow = wm * 128 + mi * 16 + ((lane >> 4) << 2) + r;
      const int gi = i0 + lrow;
      const int li = s_lbi[lrow];
      const float sqi = s_sqi[lrow];
      float nv = NEG_INF; int nix = 0;
      float pv = NEG_INF; int pix = 0;
#pragma unroll
      for (int ni = 0; ni < 4; ++ni) {
        const int cj = wn * 64 + ni * 16 + lr;
        const int gj = j0 + cj;
        const float g = acc[mi][ni][r];
        float d2 = sqi + s_sqj[cj] - 2.f * g;
        float e2 = fmaxf(d2, 0.25f);   // dist clamps (1e-4, 0.5) => dist^2 = max(d2,0.25)
        float lq = -255.f * __logf(e2) - 254.5f * __logf(1.f - 0.25f * e2);
        const bool same = (li == s_lbj[cj]);
        float cn = same ? NEG_INF : lq + gneg[(size_t)gi * B_N + gj];
        if (cn > nv) { nv = cn; nix = gj; }
        float cp = NEG_INF;
        if (same & (gi != gj)) cp = gpos[(size_t)gi * B_N + gj];
        if (cp > pv) { pv = cp; pix = gj; }
      }
#pragma unroll
      for (int off = 1; off < 16; off <<= 1) {
        float onv = __shfl_xor(nv, off); int onix = __shfl_xor(nix, off);
        if (onv > nv || (onv == nv && onix < nix)) { nv = onv; nix = onix; }
        float opv = __shfl_xor(pv, off); int opix = __shfl_xor(pix, off);
        if (opv > pv || (opv == pv && opix < pix)) { pv = opv; pix = opix; }
      }
      if (lr == 0) red[lrow * 4 + wn] = make_float4(nv, __int_as_float(nix), pv, __int_as_float(pix));
    }
  }
  __syncthreads();
  if (tid < 256) {
    float nv = NEG_INF, pv = NEG_INF; int nix = 0, pix = 0;
#pragma unroll
    for (int q = 0; q < 4; ++q) {       // ascending wn = ascending j: first-index ties
      float4 e = red[tid * 4 + q];
      int eni = __float_as_int(e.y), epi = __float_as_int(e.w);
      if (e.x > nv || (e.x == nv && eni < nix)) { nv = e.x; nix = eni; }
      if (e.z > pv || (e.z == pv && epi < pix)) { pv = e.z; pix = epi; }
    }
    part[((size_t)(ib * 16 + jb)) * 256 + tid] =
        make_float4(nv, __int_as_float(nix), pv, __int_as_float(pix));
  }
#undef STAGE
}

// ---------------- final argmax across 16 j-tiles + triplet loss ----------------
__global__ __launch_bounds__(512) void k_reduce(const float* __restrict__ batch,
                                                const float* __restrict__ beta,
                                                const int* __restrict__ labels,
                                                const float4* __restrict__ part,
                                                float* __restrict__ accum) {
  __shared__ float2 s_bsum[8];
  const int wave = threadIdx.x >> 6, lane = threadIdx.x & 63;
  const int row = blockIdx.x * 8 + wave;
  float nv = NEG_INF, pv = NEG_INF;
  int nix = 0x7fffffff, pix = 0x7fffffff;
  if (lane < 16) {
    float4 p = part[((size_t)(row >> 8) * 16 + lane) * 256 + (row & 255)];
    nv = p.x; nix = __float_as_int(p.y);
    pv = p.z; pix = __float_as_int(p.w);
  }
#pragma unroll
  for (int off = 8; off; off >>= 1) {   // lanes 0..15 reduce among themselves
    float onv = __shfl_xor(nv, off); int onix = __shfl_xor(nix, off);
    if (onv > nv || (onv == nv && onix < nix)) { nv = onv; nix = onix; }
    float opv = __shfl_xor(pv, off); int opix = __shfl_xor(pix, off);
    if (opv > pv || (opv == pv && opix < pix)) { pv = opv; pix = opix; }
  }
  nix = __shfl(nix, 0); pix = __shfl(pix, 0);

  const float* xi = batch + (size_t)row * D_DIM;
  const float* xp = batch + (size_t)pix * D_DIM;
  const float* xn = batch + (size_t)nix * D_DIM;
  float sap = 0.f, san = 0.f;
#pragma unroll
  for (int e = 0; e < 2; ++e) {
    float4 a = ((const float4*)xi)[lane * 2 + e];
    float4 p = ((const float4*)xp)[lane * 2 + e];
    float4 n = ((const float4*)xn)[lane * 2 + e];
    float dx = a.x - p.x, dy = a.y - p.y, dz = a.z - p.z, dw = a.w - p.w;
    sap += dx * dx + dy * dy + dz * dz + dw * dw;
    dx = a.x - n.x; dy = a.y - n.y; dz = a.z - n.z; dw = a.w - n.w;
    san += dx * dx + dy * dy + dz * dz + dw * dw;
  }
#pragma unroll
  for (int off = 32; off; off >>= 1) {
    sap += __shfl_xor(sap, off);
    san += __shfl_xor(san, off);
  }
  if (lane == 0) {
    float d_ap = sqrtf(sap + PAIR_EPS);
    float d_an = sqrtf(san + PAIR_EPS);
    float b = beta[labels[row]];
    float pl = fmaxf(d_ap - b + MARGIN, 0.f);
    float nl = fmaxf(b - d_an + MARGIN, 0.f);
    float cnt = (pl > 0.f ? 1.f : 0.f) + (nl > 0.f ? 1.f : 0.f);
    s_bsum[wave] = make_float2(pl + nl, cnt);
  }
  __syncthreads();
  if (threadIdx.x == 0) {
    float tot = 0.f, cnt = 0.f;
#pragma unroll
    for (int q = 0; q < 8; ++q) { tot += s_bsum[q].x; cnt += s_bsum[q].y; }
    atomicAdd(&accum[0], tot);
    atomicAdd(&accum[1], cnt);
  }
}

__global__ void k_final(const float* __restrict__ accum, float* __restrict__ out) {
  float tot = accum[0], cnt = accum[1];
  out[0] = (cnt == 0.f) ? tot : tot / cnt;
}

extern "C" void kernel_launch(void* const* d_in, const int* in_sizes, int n_in,
                              void* d_out, int out_size, void* d_ws, size_t ws_size,
                              hipStream_t stream) {
  const float* batch  = (const float*)d_in[0];
  const float* beta   = (const float*)d_in[1];
  const float* gpos   = (const float*)d_in[2];
  const float* gneg   = (const float*)d_in[3];
  const int*   labels = (const int*)d_in[4];
  float* out = (float*)d_out;

  float*          accum = (float*)d_ws;
  float*          sq    = (float*)((char*)d_ws + WS_SQ);
  unsigned short* xh    = (unsigned short*)((char*)d_ws + WS_XH);
  unsigned short* xl    = (unsigned short*)((char*)d_ws + WS_XL);
  float4*         part  = (float4*)((char*)d_ws + WS_PART);

  k_prep<<<B_N / 4, 256, 0, stream>>>(batch, accum, sq, xh, xl);
  dim3 g(16, 16);
  k_gemm<<<g, 512, 0, stream>>>(xh, xl, gpos, gneg, labels, sq, part);
  k_reduce<<<B_N / 8, 512, 0, stream>>>(batch, beta, labels, part, accum);
  k_final<<<1, 1, 0, stream>>>(accum, out);
}